// Round 4
// baseline (127.432 us; speedup 1.0000x reference)
//
#include <hip/hip_runtime.h>

#define NTOK 256
#define LOG2E 1.44269504088896340736f
#define LN_EPS 1e-5f

// Grid: 512 blocks x 256 threads. Block owns 2 batch rows; wave w (0-3) owns
// row (w>>1); each lane handles 2 query tokens (qa, qa+64). One KV broadcast
// read feeds both queries -> 1 ds_read_b128 : 12 VALU in the hot loop.
// Single __syncthreads: both attentions' KV staged up front.
__global__ __launch_bounds__(256, 2)
void att_decoder_kernel(
    const float* __restrict__ x, const float* __restrict__ m,
    const float* __restrict__ sa_w_in, const float* __restrict__ sa_b_in,
    const float* __restrict__ sa_w_out, const float* __restrict__ sa_b_out,
    const float* __restrict__ ca_w_in, const float* __restrict__ ca_b_in,
    const float* __restrict__ ca_w_out, const float* __restrict__ ca_b_out,
    const float* __restrict__ ln1_g, const float* __restrict__ ln1_b,
    const float* __restrict__ ln2_g, const float* __restrict__ ln2_b,
    const float* __restrict__ ln3_g, const float* __restrict__ ln3_b,
    const float* __restrict__ f_w1, const float* __restrict__ f_b1,
    const float* __restrict__ f_ln_g, const float* __restrict__ f_ln_b,
    const float* __restrict__ f_w2, const float* __restrict__ f_b2,
    float* __restrict__ out)
{
    const int tid = threadIdx.x;
    const int w   = tid >> 6;                 // wave 0-3
    const int l   = tid & 63;
    const int rl  = w >> 1;                   // local row 0/1
    const int row = blockIdx.x * 2 + rl;
    const int qa  = ((w & 1) << 7) + l;       // 0-127 or 128-255
    const int qb  = qa + 64;

    __shared__ float4 kv_sa[2][NTOK];         // 8 KB
    __shared__ float4 kv_ca[2][NTOK];         // 8 KB

    const float2* __restrict__ x2 = (const float2*)x;
    const float2* __restrict__ m2 = (const float2*)m;

    // ---- load 2 tokens, LN1 (d=2 closed form) ----
    float2 xa = x2[row * NTOK + qa];
    float2 xb = x2[row * NTOK + qb];
    float h0a, h1a, h0b, h1b;
    {
        float da = 0.5f * (xa.x - xa.y);
        float na = da * rsqrtf(da * da + LN_EPS);
        h0a =  na * ln1_g[0] + ln1_b[0];
        h1a = -na * ln1_g[1] + ln1_b[1];
        float db = 0.5f * (xb.x - xb.y);
        float nb = db * rsqrtf(db * db + LN_EPS);
        h0b =  nb * ln1_g[0] + ln1_b[0];
        h1b = -nb * ln1_g[1] + ln1_b[1];
    }

    // ---- stage SA-KV (from LN1(x)) and CA-KV (from m) for both tokens ----
    {
        float4 kv;
        kv.x = h0a*sa_w_in[4]  + h1a*sa_w_in[5]  + sa_b_in[2];
        kv.y = h0a*sa_w_in[6]  + h1a*sa_w_in[7]  + sa_b_in[3];
        kv.z = h0a*sa_w_in[8]  + h1a*sa_w_in[9]  + sa_b_in[4];
        kv.w = h0a*sa_w_in[10] + h1a*sa_w_in[11] + sa_b_in[5];
        kv_sa[rl][qa] = kv;
        kv.x = h0b*sa_w_in[4]  + h1b*sa_w_in[5]  + sa_b_in[2];
        kv.y = h0b*sa_w_in[6]  + h1b*sa_w_in[7]  + sa_b_in[3];
        kv.z = h0b*sa_w_in[8]  + h1b*sa_w_in[9]  + sa_b_in[4];
        kv.w = h0b*sa_w_in[10] + h1b*sa_w_in[11] + sa_b_in[5];
        kv_sa[rl][qb] = kv;

        float2 ma = m2[row * NTOK + qa];
        float2 mb = m2[row * NTOK + qb];
        kv.x = ma.x*ca_w_in[4]  + ma.y*ca_w_in[5]  + ca_b_in[2];
        kv.y = ma.x*ca_w_in[6]  + ma.y*ca_w_in[7]  + ca_b_in[3];
        kv.z = ma.x*ca_w_in[8]  + ma.y*ca_w_in[9]  + ca_b_in[4];
        kv.w = ma.x*ca_w_in[10] + ma.y*ca_w_in[11] + ca_b_in[5];
        kv_ca[rl][qa] = kv;
        kv.x = mb.x*ca_w_in[4]  + mb.y*ca_w_in[5]  + ca_b_in[2];
        kv.y = mb.x*ca_w_in[6]  + mb.y*ca_w_in[7]  + ca_b_in[3];
        kv.z = mb.x*ca_w_in[8]  + mb.y*ca_w_in[9]  + ca_b_in[4];
        kv.w = mb.x*ca_w_in[10] + mb.y*ca_w_in[11] + ca_b_in[5];
        kv_ca[rl][qb] = kv;
    }
    __syncthreads();   // the only barrier

    const float sc = 0.7071067811865476f * LOG2E;

    // ---- self-attention: both queries share each KV broadcast read ----
    {
        float qe0a = (h0a*sa_w_in[0] + h1a*sa_w_in[1] + sa_b_in[0]) * sc;
        float qe1a = (h0a*sa_w_in[2] + h1a*sa_w_in[3] + sa_b_in[1]) * sc;
        float qe0b = (h0b*sa_w_in[0] + h1b*sa_w_in[1] + sa_b_in[0]) * sc;
        float qe1b = (h0b*sa_w_in[2] + h1b*sa_w_in[3] + sa_b_in[1]) * sc;
        const float4* __restrict__ kvp = kv_sa[rl];
        float la = 0.f, a0a = 0.f, a1a = 0.f;
        float lb = 0.f, a0b = 0.f, a1b = 0.f;
        #pragma unroll 8
        for (int k = 0; k < NTOK; ++k) {
            float4 kv = kvp[k];
            float pa = __builtin_amdgcn_exp2f(qe0a * kv.x + qe1a * kv.y);
            float pb = __builtin_amdgcn_exp2f(qe0b * kv.x + qe1b * kv.y);
            la += pa; a0a += pa * kv.z; a1a += pa * kv.w;
            lb += pb; a0b += pb * kv.z; a1b += pb * kv.w;
        }
        float ra = 1.0f / la, rb = 1.0f / lb;
        a0a *= ra; a1a *= ra; a0b *= rb; a1b *= rb;
        h0a += a0a*sa_w_out[0] + a1a*sa_w_out[1] + sa_b_out[0];
        h1a += a0a*sa_w_out[2] + a1a*sa_w_out[3] + sa_b_out[1];
        h0b += a0b*sa_w_out[0] + a1b*sa_w_out[1] + sa_b_out[0];
        h1b += a0b*sa_w_out[2] + a1b*sa_w_out[3] + sa_b_out[1];
    }

    // ---- LN2 ----
    {
        float da = 0.5f * (h0a - h1a);
        float na = da * rsqrtf(da * da + LN_EPS);
        h0a =  na * ln2_g[0] + ln2_b[0];
        h1a = -na * ln2_g[1] + ln2_b[1];
        float db = 0.5f * (h0b - h1b);
        float nb = db * rsqrtf(db * db + LN_EPS);
        h0b =  nb * ln2_g[0] + ln2_b[0];
        h1b = -nb * ln2_g[1] + ln2_b[1];
    }

    // ---- cross-attention ----
    {
        float qe0a = (h0a*ca_w_in[0] + h1a*ca_w_in[1] + ca_b_in[0]) * sc;
        float qe1a = (h0a*ca_w_in[2] + h1a*ca_w_in[3] + ca_b_in[1]) * sc;
        float qe0b = (h0b*ca_w_in[0] + h1b*ca_w_in[1] + ca_b_in[0]) * sc;
        float qe1b = (h0b*ca_w_in[2] + h1b*ca_w_in[3] + ca_b_in[1]) * sc;
        const float4* __restrict__ kvp = kv_ca[rl];
        float la = 0.f, a0a = 0.f, a1a = 0.f;
        float lb = 0.f, a0b = 0.f, a1b = 0.f;
        #pragma unroll 8
        for (int k = 0; k < NTOK; ++k) {
            float4 kv = kvp[k];
            float pa = __builtin_amdgcn_exp2f(qe0a * kv.x + qe1a * kv.y);
            float pb = __builtin_amdgcn_exp2f(qe0b * kv.x + qe1b * kv.y);
            la += pa; a0a += pa * kv.z; a1a += pa * kv.w;
            lb += pb; a0b += pb * kv.z; a1b += pb * kv.w;
        }
        float ra = 1.0f / la, rb = 1.0f / lb;
        a0a *= ra; a1a *= ra; a0b *= rb; a1b *= rb;
        h0a += a0a*ca_w_out[0] + a1a*ca_w_out[1] + ca_b_out[0];
        h1a += a0a*ca_w_out[2] + a1a*ca_w_out[3] + ca_b_out[1];
        h0b += a0b*ca_w_out[0] + a1b*ca_w_out[1] + ca_b_out[0];
        h1b += a0b*ca_w_out[2] + a1b*ca_w_out[3] + ca_b_out[1];
    }

    // ---- LN3 ----
    {
        float da = 0.5f * (h0a - h1a);
        float na = da * rsqrtf(da * da + LN_EPS);
        h0a =  na * ln3_g[0] + ln3_b[0];
        h1a = -na * ln3_g[1] + ln3_b[1];
        float db = 0.5f * (h0b - h1b);
        float nb = db * rsqrtf(db * db + LN_EPS);
        h0b =  nb * ln3_g[0] + ln3_b[0];
        h1b = -nb * ln3_g[1] + ln3_b[1];
    }

    // ---- FFN (both tokens): Linear(2,10)->LN(10)->ReLU->Linear(10,2)+res ----
    #pragma unroll
    for (int tok = 0; tok < 2; ++tok) {
        float h0 = tok ? h0b : h0a;
        float h1 = tok ? h1b : h1a;
        float ff[10];
        #pragma unroll
        for (int i = 0; i < 10; ++i)
            ff[i] = h0*f_w1[2*i] + h1*f_w1[2*i+1] + f_b1[i];
        float mu = 0.f;
        #pragma unroll
        for (int i = 0; i < 10; ++i) mu += ff[i];
        mu *= 0.1f;
        float var = 0.f;
        #pragma unroll
        for (int i = 0; i < 10; ++i) { float d = ff[i] - mu; var += d * d; }
        var *= 0.1f;
        float r = rsqrtf(var + LN_EPS);
        float o0 = 0.f, o1 = 0.f;
        #pragma unroll
        for (int i = 0; i < 10; ++i) {
            float n = (ff[i] - mu) * r * f_ln_g[i] + f_ln_b[i];
            n = fmaxf(n, 0.f);
            o0 += n * f_w2[i];               // f_w2 is [2,10] row-major
            o1 += n * f_w2[10 + i];
        }
        if (tok) { h0b = h0 + o0 + f_b2[0]; h1b = h1 + o1 + f_b2[1]; }
        else     { h0a = h0 + o0 + f_b2[0]; h1a = h1 + o1 + f_b2[1]; }
    }

    float2* out2 = (float2*)out;
    out2[row * NTOK + qa] = make_float2(h0a, h1a);
    out2[row * NTOK + qb] = make_float2(h0b, h1b);
}

extern "C" void kernel_launch(void* const* d_in, const int* in_sizes, int n_in,
                              void* d_out, int out_size, void* d_ws, size_t ws_size,
                              hipStream_t stream) {
    const float* x        = (const float*)d_in[0];
    const float* m        = (const float*)d_in[1];
    const float* sa_w_in  = (const float*)d_in[2];
    const float* sa_b_in  = (const float*)d_in[3];
    const float* sa_w_out = (const float*)d_in[4];
    const float* sa_b_out = (const float*)d_in[5];
    const float* ca_w_in  = (const float*)d_in[6];
    const float* ca_b_in  = (const float*)d_in[7];
    const float* ca_w_out = (const float*)d_in[8];
    const float* ca_b_out = (const float*)d_in[9];
    const float* ln1_g    = (const float*)d_in[10];
    const float* ln1_b    = (const float*)d_in[11];
    const float* ln2_g    = (const float*)d_in[12];
    const float* ln2_b    = (const float*)d_in[13];
    const float* ln3_g    = (const float*)d_in[14];
    const float* ln3_b    = (const float*)d_in[15];
    const float* f_w1     = (const float*)d_in[16];
    const float* f_b1     = (const float*)d_in[17];
    const float* f_ln_g   = (const float*)d_in[18];
    const float* f_ln_b   = (const float*)d_in[19];
    const float* f_w2     = (const float*)d_in[20];
    const float* f_b2     = (const float*)d_in[21];

    const int nbatch = in_sizes[0] / (NTOK * 2);   // 1024
    att_decoder_kernel<<<nbatch / 2, 256, 0, stream>>>(
        x, m, sa_w_in, sa_b_in, sa_w_out, sa_b_out,
        ca_w_in, ca_b_in, ca_w_out, ca_b_out,
        ln1_g, ln1_b, ln2_g, ln2_b, ln3_g, ln3_b,
        f_w1, f_b1, f_ln_g, f_ln_b, f_w2, f_b2,
        (float*)d_out);
}